// Round 18
// baseline (332.366 us; speedup 1.0000x reference)
//
#include <hip/hip_runtime.h>
#include <hip/hip_bf16.h>

// Grouped GEMM: out[n,g,k] = sum_d x[n*8+g, d] * W[g, k, d]
// Round 18: R16 geometry (low-LDS, B-in-registers) with the producer fixed
// to 1-deep so the register allocator cannot spill (R16's failure mode).
//  - BM=256, BN=128, BK=64. 12 waves (__launch_bounds__(768,3)):
//    wid 0-7 consumers: 4M x 2N, 64x64/wave, acc 4x4 = 64 AGPR; B frags
//    (8 KiB/wave/K-tile) loaded global->reg from fragment-ordered bf16
//    image (cvt_w pre-pass, R16-correctness-verified), prefetched after
//    last use (counted wait across barrier); 4 same-wc waves L1-broadcast.
//  - wid 8-11 producers: stage ONLY A, 1-DEEP (aL[16] = 64 regs): 16 f32x4
//    loads + cvt_pk + 8 linear ds_write_b128 per K-tile; the exposed load
//    latency sits parallel to the consumers' MFMA (specialization).
//  - LDS 64 KiB (A dbuf only): per-CU LDS/K-tile 96 KB << MFMA pipe.
//  - ONE barrier per K-tile; group-per-XCD bijective swizzle.

namespace {

constexpr int NG   = 8;
constexpr int DIN  = 1024;
constexpr int DOUT = 1024;
constexpr int BM   = 256;
constexpr int BN   = 128;
constexpr int BK   = 64;
constexpr int NKT  = DIN / BK;            // 16
constexpr int ROWB = BK * 2;              // 128 B per A-LDS row
constexpr int TILE = BM * ROWB;           // 32 KiB A tile buffer
constexpr int JTN  = DOUT / BN;           // 8 col panels
constexpr int FRAGT = 16 * 1024;          // B frag-tile bytes per (g,jt,kt)
constexpr int BTFB  = BN * ROWB;          // 16 KiB fallback B tile
constexpr size_t WSB_BYTES = (size_t)NG * JTN * NKT * FRAGT;  // 16.78 MB

typedef __attribute__((ext_vector_type(8))) short bf16x8;
typedef __attribute__((ext_vector_type(4))) float f32x4;

__device__ __forceinline__ bf16x8 pack_bf16x8v(f32x4 lo, f32x4 hi) {
  union { __hip_bfloat162 h2[4]; bf16x8 v; } p;
  p.h2[0] = __float22bfloat162_rn(make_float2(lo.x, lo.y));
  p.h2[1] = __float22bfloat162_rn(make_float2(lo.z, lo.w));
  p.h2[2] = __float22bfloat162_rn(make_float2(hi.x, hi.y));
  p.h2[3] = __float22bfloat162_rn(make_float2(hi.z, hi.w));
  return p.v;
}

#define FENCE() asm volatile("" ::: "memory")
#define BAR()   do { FENCE(); __builtin_amdgcn_s_barrier(); FENCE(); } while (0)
#define LGKM0() asm volatile("s_waitcnt lgkmcnt(0)" ::: "memory")
#define MFMA_(a, b, c) __builtin_amdgcn_mfma_f32_16x16x32_bf16((a), (b), (c), 0, 0, 0)

// ---------------- cvt_w: W f32 -> bf16 fragment-ordered image ---------------
// (R16-verified.) tile(g, jt:8, kt:16) = 16 KiB = 16 frags f=(wc*4+n)*2+ks
// (wc<2) x 64 lanes x 16 B.
// Granule = W[g, jt*128+wc*64+n*16+(l&15), kt*64+ks*32+(l>>4)*8 ..+8).
__global__ __launch_bounds__(256)
void cvt_w_kernel(const float* __restrict__ W, char* __restrict__ wsB) {
  const int q    = (int)blockIdx.x * 256 + (int)threadIdx.x;
  const int tile = q >> 10;            // (g*8+jt)*16+kt; 1024 granules/tile
  const int f    = (q >> 6) & 15;
  const int l    = q & 63;
  const int g    = tile >> 7;
  const int jt   = (tile >> 4) & 7;
  const int kt   = tile & 15;
  const int wc   = f >> 3;
  const int n    = (f >> 1) & 3;
  const int ks   = f & 1;

  const int row = jt * BN + wc * 64 + n * 16 + (l & 15);
  const int col = kt * BK + ks * 32 + (l >> 4) * 8;
  const float* src = W + (size_t)(g * DOUT + row) * DIN + col;
  f32x4 lo = *(const f32x4*)(src);
  f32x4 hi = *(const f32x4*)(src + 4);
  *(bf16x8*)(wsB + (size_t)q * 16) = pack_bf16x8v(lo, hi);
}

// ---------------- producer helpers (A only, 1-deep) -------------------------
#define ISSUE_A1(TT)                                                           \
  { const float* Ai = aSrc + (size_t)(TT) * BK;                                \
    _Pragma("unroll")                                                          \
    for (int p = 0; p < 8; ++p) {                                              \
      aL[2 * p]     = *(const f32x4*)(Ai + p * ARSTR);                         \
      aL[2 * p + 1] = *(const f32x4*)(Ai + p * ARSTR + 4);                     \
    } }

#define WRITE_A1(DBUF)                                                         \
  { _Pragma("unroll")                                                          \
    for (int p = 0; p < 8; ++p)                                                \
      *(bf16x8*)((DBUF) + dst0 + p * 4096) =                                   \
          pack_bf16x8v(aL[2 * p], aL[2 * p + 1]); }

// ---------------- gemm ------------------------------------------------------
template <bool WSB>
__global__ __launch_bounds__(768, 3)
void gemm_ws(const float* __restrict__ X, const float* __restrict__ W,
             const char* __restrict__ wsB, float* __restrict__ O) {
  extern __shared__ char smem[];
  char* const smA = smem;                  // [2][256][64] bf16, swizzled
  char* const smB = smem + 2 * TILE;       // fallback only (WSB=false)

  // ---- block mapping: group == XCD (2048 blocks, 256/XCD), bijective
  const int bid = (int)blockIdx.x;
  const int swz = (bid & 7) * 256 + (bid >> 3);
  const int jt = swz & 7;                  // col panel [0,8) fastest (X reuse)
  const int it = (swz >> 3) & 31;          // row tile  [0,32)
  const int g  = swz >> 8;                 // group     [0,8)  == XCD

  const int n0 = it * BM;
  const int c0 = jt * BN;

  const int tid  = (int)threadIdx.x;
  const int lane = tid & 63;
  const int wid  = tid >> 6;               // 0-7 consumers, 8-11 producers

  if (wid < 8) {
    // ================= consumers =================
    const int wr = wid >> 1;               // M quarter [0,4)
    const int wc = wid & 1;                // N half    [0,2)
    const int fr = lane & 15;
    const int fq = lane >> 4;
    const int colx0 = ((fq       ^ (fr & 7)) << 4);   // ks=0 granules 0-3
    const int colx1 = (((4 + fq) ^ (fr & 7)) << 4);   // ks=1 granules 4-7
    const int aRow0 = (wr * 64 + fr) * ROWB;

    // B fragment stream base (this wave's 8 KiB slice per K-tile)
    const char* BgF = wsB + (size_t)((g * JTN + jt) * NKT) * FRAGT
                          + (size_t)wc * 8 * 1024 + lane * 16;

    f32x4 acc[4][4];
#pragma unroll
    for (int m = 0; m < 4; ++m)
#pragma unroll
      for (int n = 0; n < 4; ++n) acc[m][n] = (f32x4){0.f, 0.f, 0.f, 0.f};

    bf16x8 bfr[4][2];
    if (WSB) {
#pragma unroll
      for (int n = 0; n < 4; ++n)
#pragma unroll
        for (int ks = 0; ks < 2; ++ks)
          bfr[n][ks] = *(const bf16x8*)(BgF + (n * 2 + ks) * 1024);
    }

    BAR();   // matches producer prologue barrier

    for (int t = 0; t < NKT; ++t) {
      char* const cA = smA + (t & 1) * TILE;
      char* const cB = smB + (t & 1) * BTFB;   // fallback only
#pragma unroll
      for (int ks = 0; ks < 2; ++ks) {
        const int cx = ks ? colx1 : colx0;
        if (!WSB) {
#pragma unroll
          for (int n = 0; n < 4; ++n)
            bfr[n][ks] =
                *(const bf16x8*)(cB + (wc * 64 + n * 16 + fr) * ROWB + cx);
        }
        __builtin_amdgcn_s_setprio(1);
#pragma unroll
        for (int m = 0; m < 4; ++m) {
          bf16x8 am = *(const bf16x8*)(cA + aRow0 + m * 2048 + cx);
#pragma unroll
          for (int n = 0; n < 4; ++n)
            acc[m][n] = MFMA_(am, bfr[n][ks], acc[m][n]);
        }
        __builtin_amdgcn_s_setprio(0);
      }
      // prefetch next tile's B frags right after last use; counted wait
      // lands at first MFMA of t+1 (loads in flight across the barrier)
      if (WSB && t + 1 < NKT) {
        const char* Bn = BgF + (size_t)(t + 1) * FRAGT;
#pragma unroll
        for (int n = 0; n < 4; ++n)
#pragma unroll
          for (int ks = 0; ks < 2; ++ks)
            bfr[n][ks] = *(const bf16x8*)(Bn + (n * 2 + ks) * 1024);
      }
      if (t + 1 < NKT) BAR();
    }

    // ---- epilogue: C/D layout col = lane&15, row = (lane>>4)*4 + reg (m89)
#pragma unroll
    for (int m = 0; m < 4; ++m) {
#pragma unroll
      for (int r = 0; r < 4; ++r) {
        const int row = wr * 64 + m * 16 + fq * 4 + r;
        float* orow = O + ((size_t)(n0 + row) * NG + g) * DOUT + c0 + wc * 64;
#pragma unroll
        for (int n = 0; n < 4; ++n) {
          orow[n * 16 + fr] = acc[m][n][r];
        }
      }
    }
  } else {
    // ================= producers (4 waves, 256 threads): A only, 1-deep ====
    const int ptid = tid - 512;            // 0..255
    const int r0   = ptid >> 3;            // base row 0..31 (+ p*32)
    const int sl   = ptid & 7;             // phys granule slot
    const int lg   = sl ^ (r0 & 7);        // logical k-granule (32%8==0)
    const int dst0 = ptid * 16;            // linear LDS dest

    const float* aSrc = X + ((size_t)(n0 + r0) * NG + g) * DIN + lg * 8;
    constexpr size_t ARSTR = (size_t)32 * NG * DIN;   // +32 tile rows

    f32x4 aL[16];

    if (WSB) {
      // ---- prologue: stage A(0); publish
      ISSUE_A1(0);
      FENCE();
      WRITE_A1(smA);                       // implicit full wait on own loads
      LGKM0();
      BAR();

      for (int t = 0; t + 1 < NKT; ++t) {
        char* const nA = smA + ((t + 1) & 1) * TILE;
        ISSUE_A1(t + 1);
        FENCE();
        WRITE_A1(nA);
        LGKM0();
        BAR();
      }
      // 1 + 15 barriers == consumer's 16.
    } else {
      // ---- fallback (no ws): stage A and B (128x64) 1-deep.
      // B granule q = ptid*4+j: row q>>3, phys slot q&7, logical ^(row&7).
      f32x4 bL[8];
      const float* bBase = W + (size_t)(g * DOUT + c0) * DIN;
      ISSUE_A1(0);
#pragma unroll
      for (int j = 0; j < 4; ++j) {
        const int q   = ptid * 4 + j;
        const int br  = q >> 3;
        const int blg = (q & 7) ^ (br & 7);
        const float* s = bBase + (size_t)br * DIN + blg * 8;
        bL[2 * j]     = *(const f32x4*)(s);
        bL[2 * j + 1] = *(const f32x4*)(s + 4);
      }
      FENCE();
      WRITE_A1(smA);
#pragma unroll
      for (int j = 0; j < 4; ++j)
        *(bf16x8*)(smB + (ptid * 4 + j) * 16) =
            pack_bf16x8v(bL[2 * j], bL[2 * j + 1]);
      LGKM0();
      BAR();
      for (int t = 0; t + 1 < NKT; ++t) {
        char* const nA = smA + ((t + 1) & 1) * TILE;
        char* const nB = smB + ((t + 1) & 1) * BTFB;
        ISSUE_A1(t + 1);
#pragma unroll
        for (int j = 0; j < 4; ++j) {
          const int q   = ptid * 4 + j;
          const int br  = q >> 3;
          const int blg = (q & 7) ^ (br & 7);
          const float* s = bBase + (size_t)br * DIN + (t + 1) * BK + blg * 8;
          bL[2 * j]     = *(const f32x4*)(s);
          bL[2 * j + 1] = *(const f32x4*)(s + 4);
        }
        FENCE();
        WRITE_A1(nA);
#pragma unroll
        for (int j = 0; j < 4; ++j)
          *(bf16x8*)(nB + (ptid * 4 + j) * 16) =
              pack_bf16x8v(bL[2 * j], bL[2 * j + 1]);
        LGKM0();
        BAR();
      }
    }
  }
}

} // namespace

extern "C" void kernel_launch(void* const* d_in, const int* in_sizes, int n_in,
                              void* d_out, int out_size, void* d_ws, size_t ws_size,
                              hipStream_t stream) {
  (void)n_in; (void)out_size;
  const float* X = (const float*)d_in[0];
  const float* W = (const float*)d_in[1];
  float* O = (float*)d_out;

  const int tokens_total = in_sizes[0] / DIN;            // 65536
  const int ntok_per_g   = tokens_total / NG;            // 8192
  const int grid = NG * (ntok_per_g / BM) * (DOUT / BN); // 2048

  if (ws_size >= WSB_BYTES) {
    const int cvt_grid = (int)(WSB_BYTES / 16 / 256);    // 4096
    cvt_w_kernel<<<dim3(cvt_grid), dim3(256), 0, stream>>>(W, (char*)d_ws);
    const int lds = 2 * TILE;                            // 64 KiB (A only)
    (void)hipFuncSetAttribute((const void*)gemm_ws<true>,
                              hipFuncAttributeMaxDynamicSharedMemorySize, lds);
    gemm_ws<true><<<dim3(grid), dim3(768), lds, stream>>>(
        X, W, (const char*)d_ws, O);
  } else {
    const int lds = 2 * TILE + 2 * BTFB;                 // 96 KiB (A+B)
    (void)hipFuncSetAttribute((const void*)gemm_ws<false>,
                              hipFuncAttributeMaxDynamicSharedMemorySize, lds);
    gemm_ws<false><<<dim3(grid), dim3(768), lds, stream>>>(
        X, W, nullptr, O);
  }
}

// Round 19
// 213.023 us; speedup vs baseline: 1.5602x; 1.5602x over previous
//
#include <hip/hip_runtime.h>
#include <hip/hip_bf16.h>

// Grouped GEMM: out[n,g,k] = sum_d x[n*8+g, d] * W[g, k, d]
// FINAL (= rounds 14/17, session best: 213 us, 2x reproduced, clean counters).
// Wave specialization: 256x256 tile, BK=64, 12 waves (__launch_bounds__(768,3)).
//  - wid 0-7 consumers: pure MFMA (acc 8x4 in AGPRs) + ds_read + barrier,
//    setprio(1) around the MFMA cluster.
//  - wid 8-11 producers: A = 16 f32x4 loads + cvt_pk + 8 linear ds_write_b128,
//    2-DEEP pipeline (A(t+2) issued at t -> counted vmcnt, no latency
//    exposure); B = 8 glds16/thread from bf16 image (cvt_w pre-pass,
//    granule^(row&7) involution, L2-resident).
//  - ONE barrier per K-tile; vmcnt(16) keeps A(t+2) in flight across it.
//  - group-per-XCD bijective block swizzle; jt fastest for X L2 reuse.
// Plateau map (R14-R18): 2-deep producer requires B-in-LDS (R15/R16 spill
// with B-in-reg); 1-deep producer is latency-bound (R18). This point is the
// family optimum; residual gap to roofline is barrier lockstep at 1 block/CU.

namespace {

constexpr int NG   = 8;
constexpr int DIN  = 1024;
constexpr int DOUT = 1024;
constexpr int BM   = 256;
constexpr int BN   = 256;
constexpr int BK   = 64;
constexpr int NKT  = DIN / BK;            // 16
constexpr int ROWB = BK * 2;              // 128 B per LDS row
constexpr int TILE = BM * ROWB;           // 32 KiB per tile buffer
constexpr int LDS_BYTES = 4 * TILE;       // 128 KiB
constexpr int JTN  = DOUT / BN;           // 4
constexpr size_t WSB_BYTES = (size_t)NG * JTN * NKT * TILE;  // 16.78 MB

typedef __attribute__((ext_vector_type(8))) short bf16x8;
typedef __attribute__((ext_vector_type(4))) float f32x4;

__device__ __forceinline__ bf16x8 pack_bf16x8v(f32x4 lo, f32x4 hi) {
  union { __hip_bfloat162 h2[4]; bf16x8 v; } p;
  p.h2[0] = __float22bfloat162_rn(make_float2(lo.x, lo.y));
  p.h2[1] = __float22bfloat162_rn(make_float2(lo.z, lo.w));
  p.h2[2] = __float22bfloat162_rn(make_float2(hi.x, hi.y));
  p.h2[3] = __float22bfloat162_rn(make_float2(hi.z, hi.w));
  return p.v;
}

__device__ __forceinline__ void glds16(const void* g, void* l) {
  __builtin_amdgcn_global_load_lds(
      (const __attribute__((address_space(1))) unsigned int*)g,
      (__attribute__((address_space(3))) unsigned int*)l, 16, 0, 0);
}

#define FENCE() asm volatile("" ::: "memory")
#define BAR()   do { FENCE(); __builtin_amdgcn_s_barrier(); FENCE(); } while (0)
#define LGKM0() asm volatile("s_waitcnt lgkmcnt(0)" ::: "memory")
#define VM0()   asm volatile("s_waitcnt vmcnt(0)" ::: "memory")
#define VMC16() asm volatile("s_waitcnt vmcnt(16)" ::: "memory")
#define MFMA_(a, b, c) __builtin_amdgcn_mfma_f32_16x16x32_bf16((a), (b), (c), 0, 0, 0)

// ---------------- cvt_w: W f32 -> bf16 swizzled B-image (verified) ----------
__global__ __launch_bounds__(256)
void cvt_w_kernel(const float* __restrict__ W, char* __restrict__ wsB) {
  const int q    = (int)blockIdx.x * 256 + (int)threadIdx.x;  // u32 index
  const int tile = q >> 13;            // (g*4+jt)*16+kt; 8192 u32/tile
  const int q13  = q & 8191;
  const int r    = q13 >> 5;           // row 0..255
  const int cp   = q13 & 31;           // col-pair (bf16 cols 2cp,2cp+1)
  const int g    = tile >> 6;
  const int jt   = (tile >> 4) & 3;
  const int kt   = tile & 15;

  const float2 s = *(const float2*)(
      W + ((size_t)(g * DOUT + jt * BN + r)) * DIN + kt * 64 + 2 * cp);
  union { __hip_bfloat162 h; unsigned u; } pk;
  pk.h = __float22bfloat162_rn(make_float2(s.x, s.y));

  const int swzr = (r & 7) << 4;
  const int dstByte = r * ROWB + (((cp >> 2) * 16) ^ swzr) + (cp & 3) * 4;
  *(unsigned*)(wsB + (size_t)tile * TILE + dstByte) = pk.u;
}

// ---------------- producer helpers -----------------------------------------
#define ISSUE_A(TT, CUR)                                                       \
  { const float* Ai = aSrc + (size_t)(TT) * BK;                                \
    _Pragma("unroll")                                                          \
    for (int p = 0; p < 8; ++p) {                                              \
      aL[CUR][2 * p]     = *(const f32x4*)(Ai + p * ARSTR);                    \
      aL[CUR][2 * p + 1] = *(const f32x4*)(Ai + p * ARSTR + 4);                \
    } }

#define WRITE_A(CUR, DBUF)                                                     \
  { _Pragma("unroll")                                                          \
    for (int p = 0; p < 8; ++p)                                                \
      *(bf16x8*)((DBUF) + dst0 + p * 4096) =                                   \
          pack_bf16x8v(aL[CUR][2 * p], aL[CUR][2 * p + 1]); }

// WSB producer body for K-tile T: stage tile T+1 into buffer (T+1)&1.
// A(T+1) regs live in aL[CUR^1] (loaded at iter T-1); A(T+2) -> aL[CUR].
#define PBODY(T, CUR)                                                          \
  {                                                                            \
    char* const nA = smA + (((T) + 1) & 1) * TILE;                             \
    char* const nB = smB + (((T) + 1) & 1) * TILE;                             \
    const char* Bi = BgT + (size_t)((T) + 1) * TILE;                           \
    _Pragma("unroll")                                                          \
    for (int p = 0; p < 8; ++p)          /* B glds first (oldest) */           \
      glds16(Bi + dst0 + p * 4096, nB + dst0 + p * 4096);                      \
    FENCE();                                                                   \
    if ((T) + 2 < NKT) ISSUE_A((T) + 2, CUR);                                  \
    FENCE();                                                                   \
    WRITE_A((CUR) ^ 1, nA);              /* implicit counted vmcnt(24) */      \
    LGKM0();                                                                   \
    if ((T) + 2 < NKT) { VMC16(); } else { VM0(); }                            \
    BAR();                                                                     \
  }

// ---------------- gemm ------------------------------------------------------
template <bool WSB>
__global__ __launch_bounds__(768, 3)
void gemm_ws(const float* __restrict__ X, const float* __restrict__ W,
             const char* __restrict__ wsB, float* __restrict__ O) {
  extern __shared__ char smem[];
  char* const smA = smem;                  // [2][256][64] bf16, swizzled
  char* const smB = smem + 2 * TILE;

  // ---- block mapping: group == XCD (1024 blocks, 128/XCD), bijective
  const int bid = (int)blockIdx.x;
  const int swz = (bid & 7) * 128 + (bid >> 3);
  const int jt = swz & 3;                  // col panel [0,4) fastest (X reuse)
  const int it = (swz >> 2) & 31;          // row tile  [0,32)
  const int g  = swz >> 7;                 // group     [0,8)  == XCD

  const int n0 = it * BM;
  const int c0 = jt * BN;

  const int tid  = (int)threadIdx.x;
  const int lane = tid & 63;
  const int wid  = tid >> 6;               // 0-7 consumers, 8-11 producers

  if (wid < 8) {
    // ================= consumers: pure MFMA =================
    const int wr = (wid >> 2) & 1;
    const int wc = wid & 3;
    const int fr = lane & 15;
    const int fq = lane >> 4;
    const int colx0 = ((fq       ^ (fr & 7)) << 4);   // ks=0 granules 0-3
    const int colx1 = (((4 + fq) ^ (fr & 7)) << 4);   // ks=1 granules 4-7
    const int aRow0 = (wr * 128 + fr) * ROWB;
    const int bRow0 = (wc * 64  + fr) * ROWB;

    f32x4 acc[8][4];
#pragma unroll
    for (int m = 0; m < 8; ++m)
#pragma unroll
      for (int n = 0; n < 4; ++n) acc[m][n] = (f32x4){0.f, 0.f, 0.f, 0.f};

    BAR();   // matches producer prologue barrier

    for (int t = 0; t < NKT; ++t) {
      char* const cA = smA + (t & 1) * TILE;
      char* const cB = smB + (t & 1) * TILE;
#pragma unroll
      for (int ks = 0; ks < 2; ++ks) {
        const int cx = ks ? colx1 : colx0;
        bf16x8 bfr[4];
#pragma unroll
        for (int n = 0; n < 4; ++n)
          bfr[n] = *(const bf16x8*)(cB + bRow0 + n * 2048 + cx);
        __builtin_amdgcn_s_setprio(1);
#pragma unroll
        for (int m = 0; m < 8; ++m) {
          bf16x8 am = *(const bf16x8*)(cA + aRow0 + m * 2048 + cx);
#pragma unroll
          for (int n = 0; n < 4; ++n)
            acc[m][n] = MFMA_(am, bfr[n], acc[m][n]);
        }
        __builtin_amdgcn_s_setprio(0);
      }
      if (t + 1 < NKT) BAR();
    }

    // ---- epilogue: C/D layout col = lane&15, row = (lane>>4)*4 + reg (m89)
#pragma unroll
    for (int m = 0; m < 8; ++m) {
#pragma unroll
      for (int r = 0; r < 4; ++r) {
        const int row = wr * 128 + m * 16 + fq * 4 + r;
        float* orow = O + ((size_t)(n0 + row) * NG + g) * DOUT + c0 + wc * 64;
#pragma unroll
        for (int n = 0; n < 4; ++n) {
          orow[n * 16 + fr] = acc[m][n][r];
        }
      }
    }
  } else {
    // ================= producers (4 waves, 256 threads) =================
    const int ptid = tid - 512;            // 0..255
    const int r0   = ptid >> 3;            // base row 0..31 (+ p*32)
    const int sl   = ptid & 7;             // phys granule slot
    const int lg   = sl ^ (r0 & 7);        // logical k-granule (32%8==0)
    const int dst0 = ptid * 16;            // linear LDS dest

    const float* aSrc = X + ((size_t)(n0 + r0) * NG + g) * DIN + lg * 8;
    constexpr size_t ARSTR = (size_t)32 * NG * DIN;   // +32 tile rows
    const char* BgT = wsB + (size_t)((g * JTN + jt) * NKT) * TILE;
    const float* bSrc = W + ((size_t)(g * DOUT + c0 + r0)) * DIN + lg * 8;
    constexpr size_t BRSTR = (size_t)32 * DIN;

    f32x4 aL[2][16];

    if (WSB) {
      // ---- prologue: B(0) glds (oldest), A(0)->aL[0], A(1)->aL[1];
      //      write A(0) (implicit wait retires A(0) AND the older B(0)).
#pragma unroll
      for (int p = 0; p < 8; ++p)
        glds16(BgT + dst0 + p * 4096, smB + dst0 + p * 4096);
      FENCE();
      ISSUE_A(0, 0);
      ISSUE_A(1, 1);
      FENCE();
      WRITE_A(0, smA);                     // counted vmcnt(16): A(1) in flight
      LGKM0();
      BAR();

      for (int tt = 0; tt + 1 < NKT; tt += 2) {
        PBODY(tt, 0);                      // stages tile tt+1
        if (tt + 2 < NKT) PBODY(tt + 1, 1);
      }
      // 1 + 15 barriers == consumer's 16.
    } else {
      // ---- fallback (no ws): simple 1-deep reg-staged A and B
      f32x4 bL[16];
#pragma unroll
      for (int p = 0; p < 8; ++p) {
        aL[0][2 * p]     = *(const f32x4*)(aSrc + p * ARSTR);
        aL[0][2 * p + 1] = *(const f32x4*)(aSrc + p * ARSTR + 4);
        bL[2 * p]        = *(const f32x4*)(bSrc + p * BRSTR);
        bL[2 * p + 1]    = *(const f32x4*)(bSrc + p * BRSTR + 4);
      }
      WRITE_A(0, smA);
#pragma unroll
      for (int p = 0; p < 8; ++p)
        *(bf16x8*)(smB + dst0 + p * 4096) =
            pack_bf16x8v(bL[2 * p], bL[2 * p + 1]);
      LGKM0();
      BAR();
      for (int t = 0; t + 1 < NKT; ++t) {
        char* const nA = smA + ((t + 1) & 1) * TILE;
        char* const nB = smB + ((t + 1) & 1) * TILE;
        const float* Ai = aSrc + (size_t)(t + 1) * BK;
        const float* Bi = bSrc + (size_t)(t + 1) * BK;
#pragma unroll
        for (int p = 0; p < 8; ++p) {
          aL[0][2 * p]     = *(const f32x4*)(Ai + p * ARSTR);
          aL[0][2 * p + 1] = *(const f32x4*)(Ai + p * ARSTR + 4);
          bL[2 * p]        = *(const f32x4*)(Bi + p * BRSTR);
          bL[2 * p + 1]    = *(const f32x4*)(Bi + p * BRSTR + 4);
        }
        WRITE_A(0, nA);
#pragma unroll
        for (int p = 0; p < 8; ++p)
          *(bf16x8*)(nB + dst0 + p * 4096) =
              pack_bf16x8v(bL[2 * p], bL[2 * p + 1]);
        LGKM0();
        BAR();
      }
    }
  }
}

} // namespace

extern "C" void kernel_launch(void* const* d_in, const int* in_sizes, int n_in,
                              void* d_out, int out_size, void* d_ws, size_t ws_size,
                              hipStream_t stream) {
  (void)n_in; (void)out_size;
  const float* X = (const float*)d_in[0];
  const float* W = (const float*)d_in[1];
  float* O = (float*)d_out;

  const int tokens_total = in_sizes[0] / DIN;            // 65536
  const int ntok_per_g   = tokens_total / NG;            // 8192
  const int grid = NG * (ntok_per_g / BM) * (DOUT / BN); // 1024

  if (ws_size >= WSB_BYTES) {
    const int cvt_grid = (int)(WSB_BYTES / 4 / 256);     // 16384
    cvt_w_kernel<<<dim3(cvt_grid), dim3(256), 0, stream>>>(W, (char*)d_ws);
    (void)hipFuncSetAttribute((const void*)gemm_ws<true>,
                              hipFuncAttributeMaxDynamicSharedMemorySize,
                              LDS_BYTES);
    gemm_ws<true><<<dim3(grid), dim3(768), LDS_BYTES, stream>>>(
        X, W, (const char*)d_ws, O);
  } else {
    (void)hipFuncSetAttribute((const void*)gemm_ws<false>,
                              hipFuncAttributeMaxDynamicSharedMemorySize,
                              LDS_BYTES);
    gemm_ws<false><<<dim3(grid), dim3(768), LDS_BYTES, stream>>>(
        X, W, nullptr, O);
  }
}